// Round 1
// baseline (711.247 us; speedup 1.0000x reference)
//
#include <hip/hip_runtime.h>
#include <math.h>

// ---------------------------------------------------------------------------
// Problem: B=1024 batch, conv1d(3->64,k=5,pad=2) over T=100, LSTM(64->128) over
// 100 steps, then per-row epilogue (W1c matvec+tanh, W2, W0, LN, linear) and a
// 14x14 tile broadcast of the (B,128) result.
// ---------------------------------------------------------------------------

#define B_SIZE   1024
#define T_STEPS  100
#define HID      128
#define GATES    512   // 4*HID
#define KDIM     192   // 64 (x) + 128 (h)

// workspace layout (in floats)
#define WS_WPK     0                        // 192*128*4 = 98304
#define WS_BIAS    98304                    // 512
#define WS_W1CT    98816                    // 16384
#define WS_W2T     115200                   // 16384
#define WS_W0T     131584                   // 16384
#define WS_LINWT   147968                   // 16384
#define WS_HCONV   164352                   // 1024*100*64 = 6553600
#define WS_HFINAL  6717952                  // 1024*128 = 131072
// total = 6849024 floats = 27.4 MB

__device__ __forceinline__ float sigf(float x) { return 1.f / (1.f + __expf(-x)); }
__device__ __forceinline__ float tanhf_fast(float x) { return 2.f / (1.f + __expf(-2.f * x)) - 1.f; }

// ---------------------------------------------------------------------------
// prep: pack weights.
//  wPK[(k*128 + j)*4 + s] = W_cat[j + 128*s][k]   (s: 0=i,1=f,2=g,3=o)
//    where W_cat[g][k] = k<64 ? w_ih[g][k] : w_hh[g][k-64]
//  biasPK[j*4+s] = b_ih[g]+b_hh[g]
//  W1cT[f][hh] = W1[hh][f] + W1[hh][128+f]   (cat = [h;h] folding)
//  W2T[h][f]   = W2[f][h]
//  W0T[k][f]   = W0[f][k]
//  linWT[k][f] = lin_w[f][k]
// ---------------------------------------------------------------------------
__global__ void prep_kernel(const float* __restrict__ w_ih, const float* __restrict__ w_hh,
                            const float* __restrict__ b_ih, const float* __restrict__ b_hh,
                            const float* __restrict__ W1, const float* __restrict__ W2,
                            const float* __restrict__ W0, const float* __restrict__ lin_w,
                            float* __restrict__ ws) {
    float* wPK    = ws + WS_WPK;
    float* biasPK = ws + WS_BIAS;
    float* W1cT   = ws + WS_W1CT;
    float* W2T    = ws + WS_W2T;
    float* W0T    = ws + WS_W0T;
    float* linWT  = ws + WS_LINWT;

    int blk = blockIdx.x, tid = threadIdx.x;
    if (blk < 192) {
        int k = blk;
        int j = tid >> 2, s = tid & 3;
        int g = j + 128 * s;
        float v = (k < 64) ? w_ih[g * 64 + k] : w_hh[g * 128 + (k - 64)];
        wPK[(k * 128 + j) * 4 + s] = v;
    } else if (blk == 192) {
        if (tid < 512) {
            int j = tid >> 2, s = tid & 3;
            int g = j + 128 * s;
            biasPK[tid] = b_ih[g] + b_hh[g];
        }
    } else if (blk < 225) {
        int idx = (blk - 193) * 512 + tid;
        int f = idx >> 7, hh = idx & 127;
        W1cT[f * 128 + hh] = W1[hh * 256 + f] + W1[hh * 256 + 128 + f];
    } else if (blk < 257) {
        int idx = (blk - 225) * 512 + tid;
        int h = idx >> 7, f = idx & 127;
        W2T[h * 128 + f] = W2[f * 128 + h];
    } else if (blk < 289) {
        int idx = (blk - 257) * 512 + tid;
        int k = idx >> 7, f = idx & 127;
        W0T[k * 128 + f] = W0[f * 128 + k];
    } else {
        int idx = (blk - 289) * 512 + tid;
        int k = idx >> 7, f = idx & 127;
        linWT[k * 128 + f] = lin_w[f * 128 + k];
    }
}

// ---------------------------------------------------------------------------
// conv: agent = x[:,0] (B,3,100) -> relu(conv1d + b) -> hconv[b][t][k] (k=64)
// ---------------------------------------------------------------------------
__global__ __launch_bounds__(256) void conv_kernel(const float* __restrict__ x,
                                                   const float* __restrict__ conv_w,
                                                   const float* __restrict__ conv_b,
                                                   float* __restrict__ hconv) {
    __shared__ float sx[3][104];   // padded input, sx[c][t+2] = agent[c][t]
    __shared__ float sw[960];      // 64*3*5
    __shared__ float sb[64];
    int b = blockIdx.x, tid = threadIdx.x;

    for (int i = tid; i < 312; i += 256) {
        int c = i / 104, tp = i % 104;
        int t = tp - 2;
        sx[c][tp] = (t >= 0 && t < 100) ? x[b * 38400 + c * 100 + t] : 0.f;
    }
    for (int i = tid; i < 960; i += 256) sw[i] = conv_w[i];
    if (tid < 64) sb[tid] = conv_b[tid];
    __syncthreads();

    for (int i = tid; i < 6400; i += 256) {
        int t = i >> 6, k = i & 63;
        float a = sb[k];
#pragma unroll
        for (int c = 0; c < 3; ++c)
#pragma unroll
            for (int kk = 0; kk < 5; ++kk)
                a += sx[c][t + kk] * sw[k * 15 + c * 5 + kk];
        hconv[(b * 100 + t) * 64 + k] = fmaxf(a, 0.f);
    }
}

// ---------------------------------------------------------------------------
// lstm: 4 batch rows per block, 256 threads.
// Thread (p = tid>>7, j = tid&127) computes gates i,f,g,o at hidden index j
// for rows 2p and 2p+1, keeps c in registers, writes h to LDS for next step.
// Weights streamed from L2 as packed float4 (i,f,g,o per (k,j)).
// ---------------------------------------------------------------------------
__global__ __launch_bounds__(256) void lstm_kernel(const float* __restrict__ ws_ro,
                                                   float* __restrict__ ws) {
    const float* hconv  = ws_ro + WS_HCONV;
    const float* wPK    = ws_ro + WS_WPK;
    const float* biasPK = ws_ro + WS_BIAS;
    float* hfinal       = ws + WS_HFINAL;

    __shared__ float xh[4][KDIM];   // [row][k]; k<64: x_t, k>=64: h
    int tid = threadIdx.x;
    int b0 = blockIdx.x * 4;
    int p = tid >> 7;
    int j = tid & 127;

    float4 bias = *(const float4*)&biasPK[j * 4];
    float c0 = 0.f, c1 = 0.f;
    float h0 = 0.f, h1 = 0.f;

    for (int i = tid; i < 4 * KDIM; i += 256) ((float*)xh)[i] = 0.f;
    __syncthreads();

    const float* wp = wPK + j * 4;
    const float* xp = hconv + (size_t)b0 * 6400;

    for (int t = 0; t < T_STEPS; ++t) {
        // stage x_t for the 4 rows (64 floats each)
        {
            int r = tid >> 6, k = tid & 63;
            xh[r][k] = xp[r * 6400 + t * 64 + k];
        }
        __syncthreads();

        float ai0 = bias.x, af0 = bias.y, ag0 = bias.z, ao0 = bias.w;
        float ai1 = bias.x, af1 = bias.y, ag1 = bias.z, ao1 = bias.w;
        const float* xr0 = xh[2 * p];
        const float* xr1 = xh[2 * p + 1];

#define FMA8(W, XA, XB)                                              \
        ai0 += (W).x * (XA); af0 += (W).y * (XA);                    \
        ag0 += (W).z * (XA); ao0 += (W).w * (XA);                    \
        ai1 += (W).x * (XB); af1 += (W).y * (XB);                    \
        ag1 += (W).z * (XB); ao1 += (W).w * (XB);

#pragma unroll 2
        for (int k = 0; k < KDIM; k += 4) {
            float4 xa = *(const float4*)(xr0 + k);
            float4 xb = *(const float4*)(xr1 + k);
            float4 w0 = *(const float4*)(wp + (size_t)(k + 0) * 512);
            float4 w1 = *(const float4*)(wp + (size_t)(k + 1) * 512);
            float4 w2 = *(const float4*)(wp + (size_t)(k + 2) * 512);
            float4 w3 = *(const float4*)(wp + (size_t)(k + 3) * 512);
            FMA8(w0, xa.x, xb.x)
            FMA8(w1, xa.y, xb.y)
            FMA8(w2, xa.z, xb.z)
            FMA8(w3, xa.w, xb.w)
        }
#undef FMA8

        // pointwise LSTM cell
        float tg0 = tanhf_fast(ag0);
        c0 = sigf(af0) * c0 + sigf(ai0) * tg0;
        h0 = sigf(ao0) * tanhf_fast(c0);
        float tg1 = tanhf_fast(ag1);
        c1 = sigf(af1) * c1 + sigf(ai1) * tg1;
        h1 = sigf(ao1) * tanhf_fast(c1);

        __syncthreads();   // all k-loop reads done before overwriting h
        xh[2 * p][64 + j]     = h0;
        xh[2 * p + 1][64 + j] = h1;
    }

    hfinal[(size_t)(b0 + 2 * p) * 128 + j]     = h0;
    hfinal[(size_t)(b0 + 2 * p + 1) * 128 + j] = h1;
}

// ---------------------------------------------------------------------------
// post: per batch row: u=tanh(W1c@h); v=W2@u; res=W0@h+127v; LN; linear; tile.
// ---------------------------------------------------------------------------
__global__ __launch_bounds__(128) void post_kernel(const float* __restrict__ ws,
                                                   const float* __restrict__ ln_g,
                                                   const float* __restrict__ ln_b,
                                                   const float* __restrict__ lin_b,
                                                   float* __restrict__ out) {
    const float* hfinal = ws + WS_HFINAL;
    const float* W1cT   = ws + WS_W1CT;
    const float* W2T    = ws + WS_W2T;
    const float* W0T    = ws + WS_W0T;
    const float* linWT  = ws + WS_LINWT;

    __shared__ float sh[128], su[128], sres[128], spart[4];
    int b = blockIdx.x, f = threadIdx.x;

    sh[f] = hfinal[(size_t)b * 128 + f];
    __syncthreads();

    float acc = 0.f;
#pragma unroll 4
    for (int k = 0; k < 128; ++k) acc += W1cT[k * 128 + f] * sh[k];
    su[f] = tanhf_fast(acc);
    __syncthreads();

    float v = 0.f, r0 = 0.f;
#pragma unroll 4
    for (int k = 0; k < 128; ++k) {
        v  += W2T[k * 128 + f] * su[k];
        r0 += W0T[k * 128 + f] * sh[k];
    }
    float res = r0 + 127.f * v;

    // layernorm over the 128 lanes (2 waves)
    int lane = f & 63, wid = f >> 6;
    float s = res;
#pragma unroll
    for (int off = 32; off > 0; off >>= 1) s += __shfl_down(s, off);
    if (lane == 0) spart[wid] = s;
    __syncthreads();
    float mu = (spart[0] + spart[1]) * (1.f / 128.f);
    float d = res - mu;
    float s2 = d * d;
#pragma unroll
    for (int off = 32; off > 0; off >>= 1) s2 += __shfl_down(s2, off);
    if (lane == 0) spart[2 + wid] = s2;
    __syncthreads();
    float var = (spart[2] + spart[3]) * (1.f / 128.f);
    float rn = d * rsqrtf(var + 1e-5f) * ln_g[f] + ln_b[f];
    sres[f] = rn;
    __syncthreads();

    float o = lin_b[f];
#pragma unroll 4
    for (int k = 0; k < 128; ++k) o += linWT[k * 128 + f] * sres[k];

    // tile to (14,14)
    float* op = out + (size_t)b * 196 * 128 + f;
#pragma unroll 4
    for (int i = 0; i < 196; ++i) op[i * 128] = o;
}

// ---------------------------------------------------------------------------
extern "C" void kernel_launch(void* const* d_in, const int* in_sizes, int n_in,
                              void* d_out, int out_size, void* d_ws, size_t ws_size,
                              hipStream_t stream) {
    const float* x      = (const float*)d_in[0];
    const float* conv_w = (const float*)d_in[1];
    const float* conv_b = (const float*)d_in[2];
    const float* w_ih   = (const float*)d_in[3];
    const float* w_hh   = (const float*)d_in[4];
    const float* b_ih   = (const float*)d_in[5];
    const float* b_hh   = (const float*)d_in[6];
    const float* W1     = (const float*)d_in[7];
    const float* W2     = (const float*)d_in[8];
    const float* W0     = (const float*)d_in[9];
    const float* ln_g   = (const float*)d_in[10];
    const float* ln_b   = (const float*)d_in[11];
    const float* lin_w  = (const float*)d_in[12];
    const float* lin_b  = (const float*)d_in[13];
    float* ws  = (float*)d_ws;
    float* out = (float*)d_out;

    prep_kernel<<<dim3(321), dim3(512), 0, stream>>>(w_ih, w_hh, b_ih, b_hh,
                                                     W1, W2, W0, lin_w, ws);
    conv_kernel<<<dim3(B_SIZE), dim3(256), 0, stream>>>(x, conv_w, conv_b,
                                                        ws + WS_HCONV);
    lstm_kernel<<<dim3(B_SIZE / 4), dim3(256), 0, stream>>>(ws, ws);
    post_kernel<<<dim3(B_SIZE), dim3(128), 0, stream>>>(ws, ln_g, ln_b, lin_b, out);
}

// Round 2
// 323.393 us; speedup vs baseline: 2.1993x; 2.1993x over previous
//
#include <hip/hip_runtime.h>
#include <math.h>

// ---------------------------------------------------------------------------
// B=1024, conv1d(3->64,k=5,pad=2) T=100, LSTM(64->128) 100 steps (MFMA bf16x3),
// per-row epilogue (W1c tanh, W2, W0, LN, linear), tile to (14,14).
//
// LSTM: 64 blocks x 512 thr (8 waves). Block owns 16 batch rows. Wave w owns
// gate-cols j in [16w,16w+16), all 4 gates as 4 separate 16x16 acc tiles
// (cols ordered s*128+j), so i/f/g/o for (row,j) are the same lane across
// tiles -> pointwise c/h update is lane-local. Weights (192x512) pinned in
// VGPRs as bf16 hi+lo; gates = Ah*Bh + Ah*Bl + Al*Bh (bf16x3 ~ fp32).
// ---------------------------------------------------------------------------

#define T_STEPS 100

// workspace byte offsets
#define OFF_WHI    0u          // 98304 ushort  = 196608 B  (B-frag hi)
#define OFF_WLO    196608u     // 98304 ushort  = 196608 B  (B-frag lo)
#define OFF_BIAS   393216u     // 512 f32       = 2048 B
#define OFF_W1CT   395264u     // 16384 f32     = 65536 B
#define OFF_W2T    460800u     // 16384 f32
#define OFF_W0T    526336u     // 16384 f32
#define OFF_LINWT  591872u     // 16384 f32
#define OFF_XHI    657408u     // 100*1024*64 ushort = 13107200 B
#define OFF_XLO    13764608u   // 13107200 B
#define OFF_HFIN   26871808u   // 1024*128 f32 = 524288 B   (total 27396096 B)

typedef __attribute__((ext_vector_type(8))) short short8;
typedef __attribute__((ext_vector_type(4))) float f32x4;

__device__ __forceinline__ float sigf(float x) { return 1.f / (1.f + __expf(-x)); }
__device__ __forceinline__ float tanhf_fast(float x) { return 2.f / (1.f + __expf(-2.f * x)) - 1.f; }
__device__ __forceinline__ ushort f2bf(float f) {
    uint u = __float_as_uint(f);
    return (ushort)((u + 0x7fffu + ((u >> 16) & 1u)) >> 16);
}
__device__ __forceinline__ float bf2f(ushort h) { return __uint_as_float((uint)h << 16); }

// ---------------------------------------------------------------------------
// prep: pack LSTM weight B-fragments (hi/lo) + bias + epilogue transposes.
// B-frag element: whi[((w*6+kt)*4+s)*512 + l*8 + e] =
//   bf16hi( W_cat[g=s*128+16w+(l&15)][k=kt*32+(l>>4)*8+e] )
// ---------------------------------------------------------------------------
__global__ void prep_kernel(const float* __restrict__ w_ih, const float* __restrict__ w_hh,
                            const float* __restrict__ b_ih, const float* __restrict__ b_hh,
                            const float* __restrict__ W1, const float* __restrict__ W2,
                            const float* __restrict__ W0, const float* __restrict__ lin_w,
                            char* __restrict__ wsb) {
    ushort* whi   = (ushort*)(wsb + OFF_WHI);
    ushort* wlo   = (ushort*)(wsb + OFF_WLO);
    float*  biasv = (float*)(wsb + OFF_BIAS);
    float*  W1cT  = (float*)(wsb + OFF_W1CT);
    float*  W2T   = (float*)(wsb + OFF_W2T);
    float*  W0T   = (float*)(wsb + OFF_W0T);
    float*  linWT = (float*)(wsb + OFF_LINWT);

    int blk = blockIdx.x, tid = threadIdx.x;
    if (blk < 192) {
        int idx = blk * 512 + tid;
        int e = idx & 7;
        int l = (idx >> 3) & 63;
        int s = (idx >> 9) & 3;
        int rem = idx >> 11;           // w*6 + kt
        int kt = rem % 6, w = rem / 6;
        int g = s * 128 + 16 * w + (l & 15);
        int k = kt * 32 + (l >> 4) * 8 + e;
        float v = (k < 64) ? w_ih[g * 64 + k] : w_hh[g * 128 + (k - 64)];
        ushort hi = f2bf(v);
        whi[idx] = hi;
        wlo[idx] = f2bf(v - bf2f(hi));
    } else if (blk == 192) {
        biasv[tid] = b_ih[tid] + b_hh[tid];
    } else if (blk < 225) {
        int idx = (blk - 193) * 512 + tid;
        int f = idx >> 7, hh = idx & 127;
        W1cT[f * 128 + hh] = W1[hh * 256 + f] + W1[hh * 256 + 128 + f];
    } else if (blk < 257) {
        int idx = (blk - 225) * 512 + tid;
        int h = idx >> 7, f = idx & 127;
        W2T[h * 128 + f] = W2[f * 128 + h];
    } else if (blk < 289) {
        int idx = (blk - 257) * 512 + tid;
        int k = idx >> 7, f = idx & 127;
        W0T[k * 128 + f] = W0[f * 128 + k];
    } else {
        int idx = (blk - 289) * 512 + tid;
        int k = idx >> 7, f = idx & 127;
        linWT[k * 128 + f] = lin_w[f * 128 + k];
    }
}

// ---------------------------------------------------------------------------
// conv: agent = x[:,0] (B,3,100) -> relu(conv1d+b) -> xhi/xlo[t][b][k] bf16
// ---------------------------------------------------------------------------
__global__ __launch_bounds__(256) void conv_kernel(const float* __restrict__ x,
                                                   const float* __restrict__ conv_w,
                                                   const float* __restrict__ conv_b,
                                                   char* __restrict__ wsb) {
    ushort* xhi = (ushort*)(wsb + OFF_XHI);
    ushort* xlo = (ushort*)(wsb + OFF_XLO);
    __shared__ float sx[3][104];
    __shared__ float sw[960];
    __shared__ float sb[64];
    int b = blockIdx.x, tid = threadIdx.x;

    for (int i = tid; i < 312; i += 256) {
        int c = i / 104, tp = i % 104;
        int t = tp - 2;
        sx[c][tp] = (t >= 0 && t < 100) ? x[b * 38400 + c * 100 + t] : 0.f;
    }
    for (int i = tid; i < 960; i += 256) sw[i] = conv_w[i];
    if (tid < 64) sb[tid] = conv_b[tid];
    __syncthreads();

    for (int i = tid; i < 6400; i += 256) {
        int t = i >> 6, k = i & 63;
        float a = sb[k];
#pragma unroll
        for (int c = 0; c < 3; ++c)
#pragma unroll
            for (int kk = 0; kk < 5; ++kk)
                a += sx[c][t + kk] * sw[k * 15 + c * 5 + kk];
        a = fmaxf(a, 0.f);
        ushort hi = f2bf(a);
        int o = t * 65536 + b * 64 + k;
        xhi[o] = hi;
        xlo[o] = f2bf(a - bf2f(hi));
    }
}

// ---------------------------------------------------------------------------
// lstm_mfma: 64 blocks x 512 threads.
// ---------------------------------------------------------------------------
__global__ __launch_bounds__(512, 2) void lstm_mfma(const char* __restrict__ wsro,
                                                    char* __restrict__ wsb) {
    const ushort* whi   = (const ushort*)(wsro + OFF_WHI);
    const ushort* wlo   = (const ushort*)(wsro + OFF_WLO);
    const float*  biasv = (const float*)(wsro + OFF_BIAS);
    const ushort* xhi   = (const ushort*)(wsro + OFF_XHI);
    const ushort* xlo   = (const ushort*)(wsro + OFF_XLO);
    float* hfin = (float*)(wsb + OFF_HFIN);

    // padded stride 216 (432 B): 16B aligned, 2-way-max bank aliasing
    __shared__ ushort shh[16][216];
    __shared__ ushort shl[16][216];

    int tid = threadIdx.x;
    int w = tid >> 6, l = tid & 63;
    int b0 = blockIdx.x * 16;

    // ---- load weight fragments into registers (pinned for all 100 steps)
    short8 wh[6][4], wl_[6][4];
#pragma unroll
    for (int kt = 0; kt < 6; ++kt)
#pragma unroll
        for (int s = 0; s < 4; ++s) {
            int base = (((w * 6 + kt) * 4 + s) * 64 + l) * 8;
            wh[kt][s]  = *(const short8*)(whi + base);
            wl_[kt][s] = *(const short8*)(wlo + base);
        }

    int jl = 16 * w + (l & 15);     // this lane's gate column j
    float bv[4];
#pragma unroll
    for (int s = 0; s < 4; ++s) bv[s] = biasv[s * 128 + jl];

    int arow = l & 15;              // A-frag row
    int acol = (l >> 4) * 8;        // A-frag k-offset within a 32-wide tile
    int hrow0 = (l >> 4) * 4;       // first C/D row this lane owns

    float cst[4] = {0.f, 0.f, 0.f, 0.f};
    float hreg[4] = {0.f, 0.f, 0.f, 0.f};

    // zero LDS (h region must read as 0 at t=0)
    for (int i = tid; i < 16 * 216; i += 512) {
        ((ushort*)shh)[i] = 0;
        ((ushort*)shl)[i] = 0;
    }

    int xr = tid >> 5, xk = (tid & 31) * 2;   // x staging: 2 bf16 per thread

    for (int t = 0; t < T_STEPS; ++t) {
        __syncthreads();   // prev-step MFMA reads done (and zero-fill at t=0)

        // stage x_t (coalesced: 16 rows x 64 cols contiguous in ws)
        size_t xoff = (size_t)t * 65536 + (size_t)b0 * 64 + (size_t)tid * 2;
        uint vh = *(const uint*)(xhi + xoff);
        uint vl = *(const uint*)(xlo + xoff);
        *(uint*)&shh[xr][xk] = vh;
        *(uint*)&shl[xr][xk] = vl;

        // write h_{t-1} (hi/lo) for this lane's 4 (row,j) pairs
        if (t > 0) {
#pragma unroll
            for (int r = 0; r < 4; ++r) {
                float hv = hreg[r];
                ushort hh = f2bf(hv);
                shh[hrow0 + r][64 + jl] = hh;
                shl[hrow0 + r][64 + jl] = f2bf(hv - bf2f(hh));
            }
        }
        __syncthreads();

        f32x4 acc[4];
#pragma unroll
        for (int s = 0; s < 4; ++s) acc[s] = (f32x4){bv[s], bv[s], bv[s], bv[s]};

#pragma unroll
        for (int kt = 0; kt < 6; ++kt) {
            short8 ah = *(const short8*)&shh[arow][kt * 32 + acol];
            short8 al = *(const short8*)&shl[arow][kt * 32 + acol];
#pragma unroll
            for (int s = 0; s < 4; ++s) {
                acc[s] = __builtin_amdgcn_mfma_f32_16x16x32_bf16(ah, wh[kt][s],  acc[s], 0, 0, 0);
                acc[s] = __builtin_amdgcn_mfma_f32_16x16x32_bf16(ah, wl_[kt][s], acc[s], 0, 0, 0);
                acc[s] = __builtin_amdgcn_mfma_f32_16x16x32_bf16(al, wh[kt][s],  acc[s], 0, 0, 0);
            }
        }

        // pointwise LSTM cell (lane-local: i/f/g/o same lane across tiles)
#pragma unroll
        for (int r = 0; r < 4; ++r) {
            float gi = sigf(acc[0][r]);
            float gf = sigf(acc[1][r]);
            float gg = tanhf_fast(acc[2][r]);
            float go = sigf(acc[3][r]);
            cst[r] = gf * cst[r] + gi * gg;
            hreg[r] = go * tanhf_fast(cst[r]);
        }
    }

#pragma unroll
    for (int r = 0; r < 4; ++r)
        hfin[(size_t)(b0 + hrow0 + r) * 128 + jl] = hreg[r];
}

// ---------------------------------------------------------------------------
// post: per row: u=tanh(W1c@h); v=W2@u; res=W0@h+127v; LN; linear; tile 196x.
// ---------------------------------------------------------------------------
__global__ __launch_bounds__(128) void post_kernel(const char* __restrict__ wsb,
                                                   const float* __restrict__ ln_g,
                                                   const float* __restrict__ ln_b,
                                                   const float* __restrict__ lin_b,
                                                   float* __restrict__ out) {
    const float* hfinal = (const float*)(wsb + OFF_HFIN);
    const float* W1cT   = (const float*)(wsb + OFF_W1CT);
    const float* W2T    = (const float*)(wsb + OFF_W2T);
    const float* W0T    = (const float*)(wsb + OFF_W0T);
    const float* linWT  = (const float*)(wsb + OFF_LINWT);

    __shared__ float sh[128], su[128], sres[128], spart[4];
    int b = blockIdx.x, f = threadIdx.x;

    sh[f] = hfinal[(size_t)b * 128 + f];
    __syncthreads();

    float acc = 0.f;
#pragma unroll 4
    for (int k = 0; k < 128; ++k) acc += W1cT[k * 128 + f] * sh[k];
    su[f] = tanhf_fast(acc);
    __syncthreads();

    float v = 0.f, r0 = 0.f;
#pragma unroll 4
    for (int k = 0; k < 128; ++k) {
        v  += W2T[k * 128 + f] * su[k];
        r0 += W0T[k * 128 + f] * sh[k];
    }
    float res = r0 + 127.f * v;

    int lane = f & 63, wid = f >> 6;
    float s = res;
#pragma unroll
    for (int off = 32; off > 0; off >>= 1) s += __shfl_down(s, off);
    if (lane == 0) spart[wid] = s;
    __syncthreads();
    float mu = (spart[0] + spart[1]) * (1.f / 128.f);
    float d = res - mu;
    float s2 = d * d;
#pragma unroll
    for (int off = 32; off > 0; off >>= 1) s2 += __shfl_down(s2, off);
    if (lane == 0) spart[2 + wid] = s2;
    __syncthreads();
    float var = (spart[2] + spart[3]) * (1.f / 128.f);
    float rn = d * rsqrtf(var + 1e-5f) * ln_g[f] + ln_b[f];
    sres[f] = rn;
    __syncthreads();

    float o = lin_b[f];
#pragma unroll 4
    for (int k = 0; k < 128; ++k) o += linWT[k * 128 + f] * sres[k];

    float* op = out + (size_t)b * 196 * 128 + f;
#pragma unroll 4
    for (int i = 0; i < 196; ++i) op[i * 128] = o;
}

// ---------------------------------------------------------------------------
extern "C" void kernel_launch(void* const* d_in, const int* in_sizes, int n_in,
                              void* d_out, int out_size, void* d_ws, size_t ws_size,
                              hipStream_t stream) {
    const float* x      = (const float*)d_in[0];
    const float* conv_w = (const float*)d_in[1];
    const float* conv_b = (const float*)d_in[2];
    const float* w_ih   = (const float*)d_in[3];
    const float* w_hh   = (const float*)d_in[4];
    const float* b_ih   = (const float*)d_in[5];
    const float* b_hh   = (const float*)d_in[6];
    const float* W1     = (const float*)d_in[7];
    const float* W2     = (const float*)d_in[8];
    const float* W0     = (const float*)d_in[9];
    const float* ln_g   = (const float*)d_in[10];
    const float* ln_b   = (const float*)d_in[11];
    const float* lin_w  = (const float*)d_in[12];
    const float* lin_b  = (const float*)d_in[13];
    char* wsb  = (char*)d_ws;
    float* out = (float*)d_out;

    prep_kernel<<<dim3(321), dim3(512), 0, stream>>>(w_ih, w_hh, b_ih, b_hh,
                                                     W1, W2, W0, lin_w, wsb);
    conv_kernel<<<dim3(1024), dim3(256), 0, stream>>>(x, conv_w, conv_b, wsb);
    lstm_mfma<<<dim3(64), dim3(512), 0, stream>>>(wsb, wsb);
    post_kernel<<<dim3(1024), dim3(128), 0, stream>>>(wsb, ln_g, ln_b, lin_b, out);
}

// Round 3
// 238.488 us; speedup vs baseline: 2.9823x; 1.3560x over previous
//
#include <hip/hip_runtime.h>
#include <math.h>

// ---------------------------------------------------------------------------
// B=1024, conv1d(3->64,k=5,pad=2) T=100, LSTM(64->128) 100 steps (MFMA bf16x3),
// per-row epilogue (W1c tanh, W2, W0, LN, linear), tile to (14,14).
//
// LSTM: 64 blocks x 512 thr (8 waves, 2/SIMD). Block owns 16 batch rows.
// Wave w owns gate-cols [16w,16w+16), 4 gates as 4 acc tiles -> pointwise is
// lane-local. Weights pinned in VGPRs (192 regs, fits 256 cap -> no spill).
// One barrier/step via double-buffered swizzled LDS; x prefetched 1 step ahead.
// ---------------------------------------------------------------------------

#define T_STEPS 100
#define LROW    208          // ushorts per LDS row (416 B, 16B-aligned)
#define PLANE   (16 * LROW)  // ushorts per [16][LROW] plane

// workspace byte offsets
#define OFF_WHI    0u          // 98304 ushort
#define OFF_WLO    196608u     // 98304 ushort
#define OFF_BIAS   393216u     // 512 f32
#define OFF_W1CT   395264u     // 16384 f32
#define OFF_W2T    460800u
#define OFF_W0T    526336u
#define OFF_LINWT  591872u
#define OFF_XHI    657408u     // 100*1024*64 ushort
#define OFF_XLO    13764608u
#define OFF_HFIN   26871808u   // 1024*128 f32  (total 27396096 B)

typedef __attribute__((ext_vector_type(8))) short short8;
typedef __attribute__((ext_vector_type(4))) float f32x4;

__device__ __forceinline__ float frcp(float x) { return __builtin_amdgcn_rcpf(x); }
__device__ __forceinline__ float sigf(float x) { return frcp(1.f + __expf(-x)); }
__device__ __forceinline__ float tanhf_fast(float x) { return 2.f * frcp(1.f + __expf(-2.f * x)) - 1.f; }
__device__ __forceinline__ ushort f2bf(float f) {
    uint u = __float_as_uint(f);
    return (ushort)((u + 0x7fffu + ((u >> 16) & 1u)) >> 16);
}
__device__ __forceinline__ float bf2f(ushort h) { return __uint_as_float((uint)h << 16); }

// ---------------------------------------------------------------------------
// prep: pack LSTM weight B-fragments (hi/lo) + bias + epilogue transposes.
// ---------------------------------------------------------------------------
__global__ void prep_kernel(const float* __restrict__ w_ih, const float* __restrict__ w_hh,
                            const float* __restrict__ b_ih, const float* __restrict__ b_hh,
                            const float* __restrict__ W1, const float* __restrict__ W2,
                            const float* __restrict__ W0, const float* __restrict__ lin_w,
                            char* __restrict__ wsb) {
    ushort* whi   = (ushort*)(wsb + OFF_WHI);
    ushort* wlo   = (ushort*)(wsb + OFF_WLO);
    float*  biasv = (float*)(wsb + OFF_BIAS);
    float*  W1cT  = (float*)(wsb + OFF_W1CT);
    float*  W2T   = (float*)(wsb + OFF_W2T);
    float*  W0T   = (float*)(wsb + OFF_W0T);
    float*  linWT = (float*)(wsb + OFF_LINWT);

    int blk = blockIdx.x, tid = threadIdx.x;
    if (blk < 192) {
        int idx = blk * 512 + tid;
        int e = idx & 7;
        int l = (idx >> 3) & 63;
        int s = (idx >> 9) & 3;
        int rem = idx >> 11;           // w*6 + kt
        int kt = rem % 6, w = rem / 6;
        int g = s * 128 + 16 * w + (l & 15);
        int k = kt * 32 + (l >> 4) * 8 + e;
        float v = (k < 64) ? w_ih[g * 64 + k] : w_hh[g * 128 + (k - 64)];
        ushort hi = f2bf(v);
        whi[idx] = hi;
        wlo[idx] = f2bf(v - bf2f(hi));
    } else if (blk == 192) {
        biasv[tid] = b_ih[tid] + b_hh[tid];
    } else if (blk < 225) {
        int idx = (blk - 193) * 512 + tid;
        int f = idx >> 7, hh = idx & 127;
        W1cT[f * 128 + hh] = W1[hh * 256 + f] + W1[hh * 256 + 128 + f];
    } else if (blk < 257) {
        int idx = (blk - 225) * 512 + tid;
        int h = idx >> 7, f = idx & 127;
        W2T[h * 128 + f] = W2[f * 128 + h];
    } else if (blk < 289) {
        int idx = (blk - 257) * 512 + tid;
        int k = idx >> 7, f = idx & 127;
        W0T[k * 128 + f] = W0[f * 128 + k];
    } else {
        int idx = (blk - 289) * 512 + tid;
        int k = idx >> 7, f = idx & 127;
        linWT[k * 128 + f] = lin_w[f * 128 + k];
    }
}

// ---------------------------------------------------------------------------
// conv: agent = x[:,0] (B,3,100) -> relu(conv1d+b) -> xhi/xlo[t][b][k] bf16
// ---------------------------------------------------------------------------
__global__ __launch_bounds__(256) void conv_kernel(const float* __restrict__ x,
                                                   const float* __restrict__ conv_w,
                                                   const float* __restrict__ conv_b,
                                                   char* __restrict__ wsb) {
    ushort* xhi = (ushort*)(wsb + OFF_XHI);
    ushort* xlo = (ushort*)(wsb + OFF_XLO);
    __shared__ float sx[3][104];
    __shared__ float sw[960];
    __shared__ float sb[64];
    int b = blockIdx.x, tid = threadIdx.x;

    for (int i = tid; i < 312; i += 256) {
        int c = i / 104, tp = i % 104;
        int t = tp - 2;
        sx[c][tp] = (t >= 0 && t < 100) ? x[b * 38400 + c * 100 + t] : 0.f;
    }
    for (int i = tid; i < 960; i += 256) sw[i] = conv_w[i];
    if (tid < 64) sb[tid] = conv_b[tid];
    __syncthreads();

    for (int i = tid; i < 6400; i += 256) {
        int t = i >> 6, k = i & 63;
        float a = sb[k];
#pragma unroll
        for (int c = 0; c < 3; ++c)
#pragma unroll
            for (int kk = 0; kk < 5; ++kk)
                a += sx[c][t + kk] * sw[k * 15 + c * 5 + kk];
        a = fmaxf(a, 0.f);
        ushort hi = f2bf(a);
        int o = t * 65536 + b * 64 + k;
        xhi[o] = hi;
        xlo[o] = f2bf(a - bf2f(hi));
    }
}

// ---------------------------------------------------------------------------
// lstm_mfma: 64 blocks x 512 threads, 1 barrier/step, swizzled dbuf LDS.
// ---------------------------------------------------------------------------
__global__ __launch_bounds__(512, 2) void lstm_mfma(const char* __restrict__ wsro,
                                                    char* __restrict__ wsb) {
    const ushort* whi   = (const ushort*)(wsro + OFF_WHI);
    const ushort* wlo   = (const ushort*)(wsro + OFF_WLO);
    const float*  biasv = (const float*)(wsro + OFF_BIAS);
    const ushort* xhi   = (const ushort*)(wsro + OFF_XHI);
    const ushort* xlo   = (const ushort*)(wsro + OFF_XLO);
    float* hfin = (float*)(wsb + OFF_HFIN);

    __shared__ ushort L[2][2][16][LROW];   // [buf][hi/lo][row][col]

    int tid = threadIdx.x;
    int w = tid >> 6, l = tid & 63;
    int b0 = blockIdx.x * 16;

    // ---- weights pinned in regs: 48 short8 = 192 VGPRs
    short8 wh[6][4], wl_[6][4];
#pragma unroll
    for (int kt = 0; kt < 6; ++kt)
#pragma unroll
        for (int s = 0; s < 4; ++s) {
            int base = (((w * 6 + kt) * 4 + s) * 64 + l) * 8;
            wh[kt][s]  = *(const short8*)(whi + base);
            wl_[kt][s] = *(const short8*)(wlo + base);
        }

    int jl = 16 * w + (l & 15);
    float bv[4];
#pragma unroll
    for (int s = 0; s < 4; ++s) bv[s] = biasv[s * 128 + jl];

    int arow = l & 15;
    uint rbase = (uint)arow * (LROW * 2) + (uint)((l >> 4) * 16);  // + kt*64, ^rsw
    uint rsw   = (uint)(arow & 7) << 4;
    int hrow0 = (l >> 4) * 4;

    // x staging address (byte offset within a plane), swizzled
    int xr = tid >> 5;
    uint xw = ((uint)xr * (LROW * 2) + (uint)(tid & 31) * 4) ^ ((uint)(xr & 7) << 4);

    // h write offsets for r=0..3
    uint hwa[4];
#pragma unroll
    for (int r = 0; r < 4; ++r) {
        uint row = (uint)(hrow0 + r);
        hwa[r] = (row * (LROW * 2) + 128u + 2u * (uint)jl) ^ ((row & 7u) << 4);
    }

    float cst[4]  = {0.f, 0.f, 0.f, 0.f};
    float hreg[4] = {0.f, 0.f, 0.f, 0.f};

    // zero LDS (h regions must read 0 at t=0; x region overwritten below)
    for (int i = tid; i < 2 * 2 * PLANE; i += 512) ((ushort*)L)[i] = 0;

    // prefetch x(0)
    size_t xoff0 = (size_t)b0 * 64 + (size_t)tid * 2;
    uint vxh = *(const uint*)(xhi + xoff0);
    uint vxl = *(const uint*)(xlo + xoff0);
    __syncthreads();                      // zeros visible
    *(uint*)((char*)&L[0][0][0][0] + xw) = vxh;
    *(uint*)((char*)&L[0][1][0][0] + xw) = vxl;
    // prefetch x(1)
    vxh = *(const uint*)(xhi + xoff0 + 65536);
    vxl = *(const uint*)(xlo + xoff0 + 65536);
    __syncthreads();                      // x(0) visible

    for (int t = 0; t < T_STEPS; ++t) {
        int p = t & 1;
        const char* ph = (const char*)&L[p][0][0][0];
        const char* pl = (const char*)&L[p][1][0][0];

        f32x4 acc[4];
#pragma unroll
        for (int s = 0; s < 4; ++s) acc[s] = (f32x4){bv[s], bv[s], bv[s], bv[s]};

        // software-pipelined per-kt: read A-frags, 12 MFMAs (3 splits x 4 gates)
        short8 ah = *(const short8*)(ph + (rbase ^ rsw));
        short8 al = *(const short8*)(pl + (rbase ^ rsw));
#pragma unroll
        for (int kt = 0; kt < 6; ++kt) {
            short8 ahn, aln;
            if (kt < 5) {
                uint ra = (rbase + (uint)(kt + 1) * 64) ^ rsw;
                ahn = *(const short8*)(ph + ra);
                aln = *(const short8*)(pl + ra);
            }
#pragma unroll
            for (int s = 0; s < 4; ++s)
                acc[s] = __builtin_amdgcn_mfma_f32_16x16x32_bf16(ah, wh[kt][s], acc[s], 0, 0, 0);
#pragma unroll
            for (int s = 0; s < 4; ++s)
                acc[s] = __builtin_amdgcn_mfma_f32_16x16x32_bf16(ah, wl_[kt][s], acc[s], 0, 0, 0);
#pragma unroll
            for (int s = 0; s < 4; ++s)
                acc[s] = __builtin_amdgcn_mfma_f32_16x16x32_bf16(al, wh[kt][s], acc[s], 0, 0, 0);
            if (kt < 5) { ah = ahn; al = aln; }
        }

        // pointwise LSTM cell (lane-local)
#pragma unroll
        for (int r = 0; r < 4; ++r) {
            float gi = sigf(acc[0][r]);
            float gf = sigf(acc[1][r]);
            float gg = tanhf_fast(acc[2][r]);
            float go = sigf(acc[3][r]);
            cst[r] = gf * cst[r] + gi * gg;
            hreg[r] = go * tanhf_fast(cst[r]);
        }

        if (t < T_STEPS - 1) {
            char* qh = (char*)&L[p ^ 1][0][0][0];
            char* ql = (char*)&L[p ^ 1][1][0][0];
            // stage x(t+1) from prefetch regs
            *(uint*)(qh + xw) = vxh;
            *(uint*)(ql + xw) = vxl;
            // stage h(t) hi/lo
#pragma unroll
            for (int r = 0; r < 4; ++r) {
                float hv = hreg[r];
                ushort hh = f2bf(hv);
                *(ushort*)(qh + hwa[r]) = hh;
                *(ushort*)(ql + hwa[r]) = f2bf(hv - bf2f(hh));
            }
            // issue prefetch x(t+2)
            int tn = (t + 2 < T_STEPS) ? t + 2 : T_STEPS - 1;
            vxh = *(const uint*)(xhi + xoff0 + (size_t)tn * 65536);
            vxl = *(const uint*)(xlo + xoff0 + (size_t)tn * 65536);
            __syncthreads();
        }
    }

#pragma unroll
    for (int r = 0; r < 4; ++r)
        hfin[(size_t)(b0 + hrow0 + r) * 128 + jl] = hreg[r];
}

// ---------------------------------------------------------------------------
// post: per row: u=tanh(W1c@h); v=W2@u; res=W0@h+127v; LN; linear; tile 196x.
// ---------------------------------------------------------------------------
__global__ __launch_bounds__(128) void post_kernel(const char* __restrict__ wsb,
                                                   const float* __restrict__ ln_g,
                                                   const float* __restrict__ ln_b,
                                                   const float* __restrict__ lin_b,
                                                   float* __restrict__ out) {
    const float* hfinal = (const float*)(wsb + OFF_HFIN);
    const float* W1cT   = (const float*)(wsb + OFF_W1CT);
    const float* W2T    = (const float*)(wsb + OFF_W2T);
    const float* W0T    = (const float*)(wsb + OFF_W0T);
    const float* linWT  = (const float*)(wsb + OFF_LINWT);

    __shared__ float sh[128], su[128], sres[128], spart[4];
    int b = blockIdx.x, f = threadIdx.x;

    sh[f] = hfinal[(size_t)b * 128 + f];
    __syncthreads();

    float acc = 0.f;
#pragma unroll 4
    for (int k = 0; k < 128; ++k) acc += W1cT[k * 128 + f] * sh[k];
    su[f] = tanhf_fast(acc);
    __syncthreads();

    float v = 0.f, r0 = 0.f;
#pragma unroll 4
    for (int k = 0; k < 128; ++k) {
        v  += W2T[k * 128 + f] * su[k];
        r0 += W0T[k * 128 + f] * sh[k];
    }
    float res = r0 + 127.f * v;

    int lane = f & 63, wid = f >> 6;
    float s = res;
#pragma unroll
    for (int off = 32; off > 0; off >>= 1) s += __shfl_down(s, off);
    if (lane == 0) spart[wid] = s;
    __syncthreads();
    float mu = (spart[0] + spart[1]) * (1.f / 128.f);
    float d = res - mu;
    float s2 = d * d;
#pragma unroll
    for (int off = 32; off > 0; off >>= 1) s2 += __shfl_down(s2, off);
    if (lane == 0) spart[2 + wid] = s2;
    __syncthreads();
    float var = (spart[2] + spart[3]) * (1.f / 128.f);
    float rn = d * rsqrtf(var + 1e-5f) * ln_g[f] + ln_b[f];
    sres[f] = rn;
    __syncthreads();

    float o = lin_b[f];
#pragma unroll 4
    for (int k = 0; k < 128; ++k) o += linWT[k * 128 + f] * sres[k];

    float* op = out + (size_t)b * 196 * 128 + f;
#pragma unroll 4
    for (int i = 0; i < 196; ++i) op[i * 128] = o;
}

// ---------------------------------------------------------------------------
extern "C" void kernel_launch(void* const* d_in, const int* in_sizes, int n_in,
                              void* d_out, int out_size, void* d_ws, size_t ws_size,
                              hipStream_t stream) {
    const float* x      = (const float*)d_in[0];
    const float* conv_w = (const float*)d_in[1];
    const float* conv_b = (const float*)d_in[2];
    const float* w_ih   = (const float*)d_in[3];
    const float* w_hh   = (const float*)d_in[4];
    const float* b_ih   = (const float*)d_in[5];
    const float* b_hh   = (const float*)d_in[6];
    const float* W1     = (const float*)d_in[7];
    const float* W2     = (const float*)d_in[8];
    const float* W0     = (const float*)d_in[9];
    const float* ln_g   = (const float*)d_in[10];
    const float* ln_b   = (const float*)d_in[11];
    const float* lin_w  = (const float*)d_in[12];
    const float* lin_b  = (const float*)d_in[13];
    char* wsb  = (char*)d_ws;
    float* out = (float*)d_out;

    prep_kernel<<<dim3(321), dim3(512), 0, stream>>>(w_ih, w_hh, b_ih, b_hh,
                                                     W1, W2, W0, lin_w, wsb);
    conv_kernel<<<dim3(1024), dim3(256), 0, stream>>>(x, conv_w, conv_b, wsb);
    lstm_mfma<<<dim3(64), dim3(512), 0, stream>>>(wsb, wsb);
    post_kernel<<<dim3(1024), dim3(128), 0, stream>>>(wsb, ln_g, ln_b, lin_b, out);
}

// Round 4
// 238.455 us; speedup vs baseline: 2.9827x; 1.0001x over previous
//
#include <hip/hip_runtime.h>
#include <math.h>

// ---------------------------------------------------------------------------
// B=1024, conv1d(3->64,k=5,pad=2) T=100, LSTM(64->128) 100 steps (MFMA bf16x3),
// per-row epilogue (W1c tanh, W2, W0, LN, linear), tile to (14,14).
//
// LSTM: 64 blocks x 512 thr (8 waves). amdgpu_waves_per_eu(2,2) pins occupancy
// at 2 waves/SIMD so the register allocator keeps all 48 weight fragments
// (192 VGPRs) resident for the whole 100-step loop — round-3's VGPR_Count=128
// showed the compiler was spilling them (4-waves/EU heuristic), costing
// ~393KB/block/step of scratch re-reads.
// ---------------------------------------------------------------------------

#define T_STEPS 100
#define LROW    208          // ushorts per LDS row (416 B, 16B-aligned)
#define PLANE   (16 * LROW)  // ushorts per [16][LROW] plane

// workspace byte offsets
#define OFF_WHI    0u          // 98304 ushort
#define OFF_WLO    196608u     // 98304 ushort
#define OFF_BIAS   393216u     // 512 f32
#define OFF_W1CT   395264u     // 16384 f32
#define OFF_W2T    460800u
#define OFF_W0T    526336u
#define OFF_LINWT  591872u
#define OFF_XHI    657408u     // 100*1024*64 ushort
#define OFF_XLO    13764608u
#define OFF_HFIN   26871808u   // 1024*128 f32  (total 27396096 B)

typedef __attribute__((ext_vector_type(8))) short short8;
typedef __attribute__((ext_vector_type(4))) float f32x4;

__device__ __forceinline__ float frcp(float x) { return __builtin_amdgcn_rcpf(x); }
__device__ __forceinline__ float sigf(float x) { return frcp(1.f + __expf(-x)); }
__device__ __forceinline__ float tanhf_fast(float x) { return 2.f * frcp(1.f + __expf(-2.f * x)) - 1.f; }
__device__ __forceinline__ ushort f2bf(float f) {
    uint u = __float_as_uint(f);
    return (ushort)((u + 0x7fffu + ((u >> 16) & 1u)) >> 16);
}
__device__ __forceinline__ float bf2f(ushort h) { return __uint_as_float((uint)h << 16); }

// ---------------------------------------------------------------------------
// prep: pack LSTM weight B-fragments (hi/lo) + bias + epilogue transposes.
// ---------------------------------------------------------------------------
__global__ void prep_kernel(const float* __restrict__ w_ih, const float* __restrict__ w_hh,
                            const float* __restrict__ b_ih, const float* __restrict__ b_hh,
                            const float* __restrict__ W1, const float* __restrict__ W2,
                            const float* __restrict__ W0, const float* __restrict__ lin_w,
                            char* __restrict__ wsb) {
    ushort* whi   = (ushort*)(wsb + OFF_WHI);
    ushort* wlo   = (ushort*)(wsb + OFF_WLO);
    float*  biasv = (float*)(wsb + OFF_BIAS);
    float*  W1cT  = (float*)(wsb + OFF_W1CT);
    float*  W2T   = (float*)(wsb + OFF_W2T);
    float*  W0T   = (float*)(wsb + OFF_W0T);
    float*  linWT = (float*)(wsb + OFF_LINWT);

    int blk = blockIdx.x, tid = threadIdx.x;
    if (blk < 192) {
        int idx = blk * 512 + tid;
        int e = idx & 7;
        int l = (idx >> 3) & 63;
        int s = (idx >> 9) & 3;
        int rem = idx >> 11;           // w*6 + kt
        int kt = rem % 6, w = rem / 6;
        int g = s * 128 + 16 * w + (l & 15);
        int k = kt * 32 + (l >> 4) * 8 + e;
        float v = (k < 64) ? w_ih[g * 64 + k] : w_hh[g * 128 + (k - 64)];
        ushort hi = f2bf(v);
        whi[idx] = hi;
        wlo[idx] = f2bf(v - bf2f(hi));
    } else if (blk == 192) {
        biasv[tid] = b_ih[tid] + b_hh[tid];
    } else if (blk < 225) {
        int idx = (blk - 193) * 512 + tid;
        int f = idx >> 7, hh = idx & 127;
        W1cT[f * 128 + hh] = W1[hh * 256 + f] + W1[hh * 256 + 128 + f];
    } else if (blk < 257) {
        int idx = (blk - 225) * 512 + tid;
        int h = idx >> 7, f = idx & 127;
        W2T[h * 128 + f] = W2[f * 128 + h];
    } else if (blk < 289) {
        int idx = (blk - 257) * 512 + tid;
        int k = idx >> 7, f = idx & 127;
        W0T[k * 128 + f] = W0[f * 128 + k];
    } else {
        int idx = (blk - 289) * 512 + tid;
        int k = idx >> 7, f = idx & 127;
        linWT[k * 128 + f] = lin_w[f * 128 + k];
    }
}

// ---------------------------------------------------------------------------
// conv: agent = x[:,0] (B,3,100) -> relu(conv1d+b) -> xhi/xlo[t][b][k] bf16
// ---------------------------------------------------------------------------
__global__ __launch_bounds__(256) void conv_kernel(const float* __restrict__ x,
                                                   const float* __restrict__ conv_w,
                                                   const float* __restrict__ conv_b,
                                                   char* __restrict__ wsb) {
    ushort* xhi = (ushort*)(wsb + OFF_XHI);
    ushort* xlo = (ushort*)(wsb + OFF_XLO);
    __shared__ float sx[3][104];
    __shared__ float sw[960];
    __shared__ float sb[64];
    int b = blockIdx.x, tid = threadIdx.x;

    for (int i = tid; i < 312; i += 256) {
        int c = i / 104, tp = i % 104;
        int t = tp - 2;
        sx[c][tp] = (t >= 0 && t < 100) ? x[b * 38400 + c * 100 + t] : 0.f;
    }
    for (int i = tid; i < 960; i += 256) sw[i] = conv_w[i];
    if (tid < 64) sb[tid] = conv_b[tid];
    __syncthreads();

    for (int i = tid; i < 6400; i += 256) {
        int t = i >> 6, k = i & 63;
        float a = sb[k];
#pragma unroll
        for (int c = 0; c < 3; ++c)
#pragma unroll
            for (int kk = 0; kk < 5; ++kk)
                a += sx[c][t + kk] * sw[k * 15 + c * 5 + kk];
        a = fmaxf(a, 0.f);
        ushort hi = f2bf(a);
        int o = t * 65536 + b * 64 + k;
        xhi[o] = hi;
        xlo[o] = f2bf(a - bf2f(hi));
    }
}

// ---------------------------------------------------------------------------
// lstm_mfma: 64 blocks x 512 threads, weights pinned in VGPRs, 1 barrier/step.
// ---------------------------------------------------------------------------
__global__ __launch_bounds__(512)
__attribute__((amdgpu_waves_per_eu(2, 2)))
void lstm_mfma(const char* __restrict__ wsro, char* __restrict__ wsb) {
    const ushort* whi   = (const ushort*)(wsro + OFF_WHI);
    const ushort* wlo   = (const ushort*)(wsro + OFF_WLO);
    const float*  biasv = (const float*)(wsro + OFF_BIAS);
    const ushort* xhi   = (const ushort*)(wsro + OFF_XHI);
    const ushort* xlo   = (const ushort*)(wsro + OFF_XLO);
    float* hfin = (float*)(wsb + OFF_HFIN);

    __shared__ ushort L[2][2][16][LROW];   // [buf][hi/lo][row][col]

    int tid = threadIdx.x;
    int w = tid >> 6, l = tid & 63;
    int b0 = blockIdx.x * 16;

    // ---- weights pinned in regs: 48 short8 = 192 VGPRs
    short8 wh[6][4], wl_[6][4];
#pragma unroll
    for (int kt = 0; kt < 6; ++kt)
#pragma unroll
        for (int s = 0; s < 4; ++s) {
            int base = (((w * 6 + kt) * 4 + s) * 64 + l) * 8;
            wh[kt][s]  = *(const short8*)(whi + base);
            wl_[kt][s] = *(const short8*)(wlo + base);
        }

    int jl = 16 * w + (l & 15);
    float bv[4];
#pragma unroll
    for (int s = 0; s < 4; ++s) bv[s] = biasv[s * 128 + jl];

    int arow = l & 15;
    uint rbase = (uint)arow * (LROW * 2) + (uint)((l >> 4) * 16);  // + kt*64, ^rsw
    uint rsw   = (uint)(arow & 7) << 4;
    int hrow0 = (l >> 4) * 4;

    // x staging address (byte offset within a plane), swizzled
    int xr = tid >> 5;
    uint xw = ((uint)xr * (LROW * 2) + (uint)(tid & 31) * 4) ^ ((uint)(xr & 7) << 4);

    // h write offsets for r=0..3
    uint hwa[4];
#pragma unroll
    for (int r = 0; r < 4; ++r) {
        uint row = (uint)(hrow0 + r);
        hwa[r] = (row * (LROW * 2) + 128u + 2u * (uint)jl) ^ ((row & 7u) << 4);
    }

    float cst[4]  = {0.f, 0.f, 0.f, 0.f};
    float hreg[4] = {0.f, 0.f, 0.f, 0.f};

    // zero LDS (h regions must read 0 at t=0; x region overwritten below)
    for (int i = tid; i < 2 * 2 * PLANE; i += 512) ((ushort*)L)[i] = 0;

    // prefetch x(0)
    size_t xoff0 = (size_t)b0 * 64 + (size_t)tid * 2;
    uint vxh = *(const uint*)(xhi + xoff0);
    uint vxl = *(const uint*)(xlo + xoff0);
    __syncthreads();                      // zeros visible
    *(uint*)((char*)&L[0][0][0][0] + xw) = vxh;
    *(uint*)((char*)&L[0][1][0][0] + xw) = vxl;
    // prefetch x(1)
    vxh = *(const uint*)(xhi + xoff0 + 65536);
    vxl = *(const uint*)(xlo + xoff0 + 65536);
    __syncthreads();                      // x(0) visible

    for (int t = 0; t < T_STEPS; ++t) {
        int p = t & 1;
        const char* ph = (const char*)&L[p][0][0][0];
        const char* pl = (const char*)&L[p][1][0][0];

        f32x4 acc[4];
#pragma unroll
        for (int s = 0; s < 4; ++s) acc[s] = (f32x4){bv[s], bv[s], bv[s], bv[s]};

#pragma unroll
        for (int kt = 0; kt < 6; ++kt) {
            uint ra = (rbase + (uint)kt * 64) ^ rsw;
            short8 ah = *(const short8*)(ph + ra);
            short8 al = *(const short8*)(pl + ra);
#pragma unroll
            for (int s = 0; s < 4; ++s)
                acc[s] = __builtin_amdgcn_mfma_f32_16x16x32_bf16(ah, wh[kt][s], acc[s], 0, 0, 0);
#pragma unroll
            for (int s = 0; s < 4; ++s)
                acc[s] = __builtin_amdgcn_mfma_f32_16x16x32_bf16(ah, wl_[kt][s], acc[s], 0, 0, 0);
#pragma unroll
            for (int s = 0; s < 4; ++s)
                acc[s] = __builtin_amdgcn_mfma_f32_16x16x32_bf16(al, wh[kt][s], acc[s], 0, 0, 0);
        }

        // pointwise LSTM cell (lane-local)
#pragma unroll
        for (int r = 0; r < 4; ++r) {
            float gi = sigf(acc[0][r]);
            float gf = sigf(acc[1][r]);
            float gg = tanhf_fast(acc[2][r]);
            float go = sigf(acc[3][r]);
            cst[r] = gf * cst[r] + gi * gg;
            hreg[r] = go * tanhf_fast(cst[r]);
        }

        if (t < T_STEPS - 1) {
            char* qh = (char*)&L[p ^ 1][0][0][0];
            char* ql = (char*)&L[p ^ 1][1][0][0];
            // stage x(t+1) from prefetch regs
            *(uint*)(qh + xw) = vxh;
            *(uint*)(ql + xw) = vxl;
            // stage h(t) hi/lo
#pragma unroll
            for (int r = 0; r < 4; ++r) {
                float hv = hreg[r];
                ushort hh = f2bf(hv);
                *(ushort*)(qh + hwa[r]) = hh;
                *(ushort*)(ql + hwa[r]) = f2bf(hv - bf2f(hh));
            }
            // issue prefetch x(t+2)
            int tn = (t + 2 < T_STEPS) ? t + 2 : T_STEPS - 1;
            vxh = *(const uint*)(xhi + xoff0 + (size_t)tn * 65536);
            vxl = *(const uint*)(xlo + xoff0 + (size_t)tn * 65536);
            __syncthreads();
        }
    }

#pragma unroll
    for (int r = 0; r < 4; ++r)
        hfin[(size_t)(b0 + hrow0 + r) * 128 + jl] = hreg[r];
}

// ---------------------------------------------------------------------------
// post: per row: u=tanh(W1c@h); v=W2@u; res=W0@h+127v; LN; linear; tile 196x.
// ---------------------------------------------------------------------------
__global__ __launch_bounds__(128) void post_kernel(const char* __restrict__ wsb,
                                                   const float* __restrict__ ln_g,
                                                   const float* __restrict__ ln_b,
                                                   const float* __restrict__ lin_b,
                                                   float* __restrict__ out) {
    const float* hfinal = (const float*)(wsb + OFF_HFIN);
    const float* W1cT   = (const float*)(wsb + OFF_W1CT);
    const float* W2T    = (const float*)(wsb + OFF_W2T);
    const float* W0T    = (const float*)(wsb + OFF_W0T);
    const float* linWT  = (const float*)(wsb + OFF_LINWT);

    __shared__ float sh[128], su[128], sres[128], spart[4];
    int b = blockIdx.x, f = threadIdx.x;

    sh[f] = hfinal[(size_t)b * 128 + f];
    __syncthreads();

    float acc = 0.f;
#pragma unroll 4
    for (int k = 0; k < 128; ++k) acc += W1cT[k * 128 + f] * sh[k];
    su[f] = tanhf_fast(acc);
    __syncthreads();

    float v = 0.f, r0 = 0.f;
#pragma unroll 4
    for (int k = 0; k < 128; ++k) {
        v  += W2T[k * 128 + f] * su[k];
        r0 += W0T[k * 128 + f] * sh[k];
    }
    float res = r0 + 127.f * v;

    int lane = f & 63, wid = f >> 6;
    float s = res;
#pragma unroll
    for (int off = 32; off > 0; off >>= 1) s += __shfl_down(s, off);
    if (lane == 0) spart[wid] = s;
    __syncthreads();
    float mu = (spart[0] + spart[1]) * (1.f / 128.f);
    float d = res - mu;
    float s2 = d * d;
#pragma unroll
    for (int off = 32; off > 0; off >>= 1) s2 += __shfl_down(s2, off);
    if (lane == 0) spart[2 + wid] = s2;
    __syncthreads();
    float var = (spart[2] + spart[3]) * (1.f / 128.f);
    float rn = d * rsqrtf(var + 1e-5f) * ln_g[f] + ln_b[f];
    sres[f] = rn;
    __syncthreads();

    float o = lin_b[f];
#pragma unroll 4
    for (int k = 0; k < 128; ++k) o += linWT[k * 128 + f] * sres[k];

    float* op = out + (size_t)b * 196 * 128 + f;
#pragma unroll 4
    for (int i = 0; i < 196; ++i) op[i * 128] = o;
}

// ---------------------------------------------------------------------------
extern "C" void kernel_launch(void* const* d_in, const int* in_sizes, int n_in,
                              void* d_out, int out_size, void* d_ws, size_t ws_size,
                              hipStream_t stream) {
    const float* x      = (const float*)d_in[0];
    const float* conv_w = (const float*)d_in[1];
    const float* conv_b = (const float*)d_in[2];
    const float* w_ih   = (const float*)d_in[3];
    const float* w_hh   = (const float*)d_in[4];
    const float* b_ih   = (const float*)d_in[5];
    const float* b_hh   = (const float*)d_in[6];
    const float* W1     = (const float*)d_in[7];
    const float* W2     = (const float*)d_in[8];
    const float* W0     = (const float*)d_in[9];
    const float* ln_g   = (const float*)d_in[10];
    const float* ln_b   = (const float*)d_in[11];
    const float* lin_w  = (const float*)d_in[12];
    const float* lin_b  = (const float*)d_in[13];
    char* wsb  = (char*)d_ws;
    float* out = (float*)d_out;

    prep_kernel<<<dim3(321), dim3(512), 0, stream>>>(w_ih, w_hh, b_ih, b_hh,
                                                     W1, W2, W0, lin_w, wsb);
    conv_kernel<<<dim3(1024), dim3(256), 0, stream>>>(x, conv_w, conv_b, wsb);
    lstm_mfma<<<dim3(64), dim3(512), 0, stream>>>(wsb, wsb);
    post_kernel<<<dim3(1024), dim3(128), 0, stream>>>(wsb, ln_g, ln_b, lin_b, out);
}

// Round 5
// 214.132 us; speedup vs baseline: 3.3215x; 1.1136x over previous
//
#include <hip/hip_runtime.h>
#include <math.h>

// ---------------------------------------------------------------------------
// B=1024, conv1d(3->64,k=5,pad=2) T=100, LSTM(64->128) 100 steps (MFMA),
// per-row epilogue (W1c tanh, W2, W0, LN, linear), tile to (14,14).
//
// LSTM: 64 blocks x 512 thr (8 waves, 2/SIMD). Block owns 16 batch rows.
// Wave w owns gate-cols [16w,16w+16), 4 gates as 4 acc tiles -> pointwise is
// lane-local. h carried as bf16 hi+lo (bf16x3 accuracy); x carried bf16-hi
// only (error ~1e-4 << 0.04 threshold). Two independent accumulator chains
// (depth 8/6) halve dependent-MFMA latency. x prefetch issued at the TOP of
// each step so the compiler's vmcnt(0)-drain at the barrier costs ~nothing
// (round-4 issued it right before the barrier => full latency exposed/step).
// ---------------------------------------------------------------------------

#define T_STEPS 100
#define LROW    208          // ushorts per LDS row (416 B, 16B-aligned)
#define PLANE   (16 * LROW)  // ushorts per [16][LROW] plane

// workspace byte offsets
#define OFF_WHI    0u          // 98304 ushort
#define OFF_WLO    196608u     // 98304 ushort
#define OFF_BIAS   393216u     // 512 f32
#define OFF_W1CT   395264u     // 16384 f32
#define OFF_W2T    460800u
#define OFF_W0T    526336u
#define OFF_LINWT  591872u
#define OFF_XHI    657408u     // 100*1024*64 ushort
#define OFF_HFIN   26871808u   // 1024*128 f32
// ws total needed: 27396096 B (same as prior rounds)

typedef __attribute__((ext_vector_type(8))) short short8;
typedef __attribute__((ext_vector_type(4))) float f32x4;

__device__ __forceinline__ float frcp(float x) { return __builtin_amdgcn_rcpf(x); }
__device__ __forceinline__ float sigf(float x) { return frcp(1.f + __expf(-x)); }
__device__ __forceinline__ float tanhf_fast(float x) { return 2.f * frcp(1.f + __expf(-2.f * x)) - 1.f; }
__device__ __forceinline__ ushort f2bf(float f) {
    uint u = __float_as_uint(f);
    return (ushort)((u + 0x7fffu + ((u >> 16) & 1u)) >> 16);
}
__device__ __forceinline__ float bf2f(ushort h) { return __uint_as_float((uint)h << 16); }

// ---------------------------------------------------------------------------
// prep: pack LSTM weight B-fragments (hi/lo) + bias + epilogue transposes.
// ---------------------------------------------------------------------------
__global__ void prep_kernel(const float* __restrict__ w_ih, const float* __restrict__ w_hh,
                            const float* __restrict__ b_ih, const float* __restrict__ b_hh,
                            const float* __restrict__ W1, const float* __restrict__ W2,
                            const float* __restrict__ W0, const float* __restrict__ lin_w,
                            char* __restrict__ wsb) {
    ushort* whi   = (ushort*)(wsb + OFF_WHI);
    ushort* wlo   = (ushort*)(wsb + OFF_WLO);
    float*  biasv = (float*)(wsb + OFF_BIAS);
    float*  W1cT  = (float*)(wsb + OFF_W1CT);
    float*  W2T   = (float*)(wsb + OFF_W2T);
    float*  W0T   = (float*)(wsb + OFF_W0T);
    float*  linWT = (float*)(wsb + OFF_LINWT);

    int blk = blockIdx.x, tid = threadIdx.x;
    if (blk < 192) {
        int idx = blk * 512 + tid;
        int e = idx & 7;
        int l = (idx >> 3) & 63;
        int s = (idx >> 9) & 3;
        int rem = idx >> 11;           // w*6 + kt
        int kt = rem % 6, w = rem / 6;
        int g = s * 128 + 16 * w + (l & 15);
        int k = kt * 32 + (l >> 4) * 8 + e;
        float v = (k < 64) ? w_ih[g * 64 + k] : w_hh[g * 128 + (k - 64)];
        ushort hi = f2bf(v);
        whi[idx] = hi;
        wlo[idx] = f2bf(v - bf2f(hi));
    } else if (blk == 192) {
        biasv[tid] = b_ih[tid] + b_hh[tid];
    } else if (blk < 225) {
        int idx = (blk - 193) * 512 + tid;
        int f = idx >> 7, hh = idx & 127;
        W1cT[f * 128 + hh] = W1[hh * 256 + f] + W1[hh * 256 + 128 + f];
    } else if (blk < 257) {
        int idx = (blk - 225) * 512 + tid;
        int h = idx >> 7, f = idx & 127;
        W2T[h * 128 + f] = W2[f * 128 + h];
    } else if (blk < 289) {
        int idx = (blk - 257) * 512 + tid;
        int k = idx >> 7, f = idx & 127;
        W0T[k * 128 + f] = W0[f * 128 + k];
    } else {
        int idx = (blk - 289) * 512 + tid;
        int k = idx >> 7, f = idx & 127;
        linWT[k * 128 + f] = lin_w[f * 128 + k];
    }
}

// ---------------------------------------------------------------------------
// conv: agent = x[:,0] (B,3,100) -> relu(conv1d+b) -> xhi[t][b][k] bf16
// ---------------------------------------------------------------------------
__global__ __launch_bounds__(256) void conv_kernel(const float* __restrict__ x,
                                                   const float* __restrict__ conv_w,
                                                   const float* __restrict__ conv_b,
                                                   char* __restrict__ wsb) {
    ushort* xhi = (ushort*)(wsb + OFF_XHI);
    __shared__ float sx[3][104];
    __shared__ float sw[960];
    __shared__ float sb[64];
    int b = blockIdx.x, tid = threadIdx.x;

    for (int i = tid; i < 312; i += 256) {
        int c = i / 104, tp = i % 104;
        int t = tp - 2;
        sx[c][tp] = (t >= 0 && t < 100) ? x[b * 38400 + c * 100 + t] : 0.f;
    }
    for (int i = tid; i < 960; i += 256) sw[i] = conv_w[i];
    if (tid < 64) sb[tid] = conv_b[tid];
    __syncthreads();

    for (int i = tid; i < 6400; i += 256) {
        int t = i >> 6, k = i & 63;
        float a = sb[k];
#pragma unroll
        for (int c = 0; c < 3; ++c)
#pragma unroll
            for (int kk = 0; kk < 5; ++kk)
                a += sx[c][t + kk] * sw[k * 15 + c * 5 + kk];
        a = fmaxf(a, 0.f);
        xhi[t * 65536 + b * 64 + k] = f2bf(a);
    }
}

// ---------------------------------------------------------------------------
// lstm_mfma: 64 blocks x 512 threads, weights pinned in regs, 1 barrier/step.
// ---------------------------------------------------------------------------
__global__ __launch_bounds__(512)
__attribute__((amdgpu_waves_per_eu(2, 2)))
void lstm_mfma(const char* __restrict__ wsro, char* __restrict__ wsb) {
    const ushort* whi   = (const ushort*)(wsro + OFF_WHI);
    const ushort* wlo   = (const ushort*)(wsro + OFF_WLO);
    const float*  biasv = (const float*)(wsro + OFF_BIAS);
    const ushort* xhi   = (const ushort*)(wsro + OFF_XHI);
    float* hfin = (float*)(wsb + OFF_HFIN);

    __shared__ ushort L[2][2][16][LROW];   // [buf][hi/lo][row][col]

    int tid = threadIdx.x;
    int w = tid >> 6, l = tid & 63;
    int b0 = blockIdx.x * 16;

    // ---- weights pinned in regs: x-part hi only (8), h-part hi+lo (32)
    short8 wx[2][4];                  // kt 0..1 (K 0..63)
    short8 wh[4][4], wl_[4][4];       // kt 2..5 (K 64..191)
#pragma unroll
    for (int ktx = 0; ktx < 2; ++ktx)
#pragma unroll
        for (int s = 0; s < 4; ++s)
            wx[ktx][s] = *(const short8*)(whi + (((w * 6 + ktx) * 4 + s) * 64 + l) * 8);
#pragma unroll
    for (int kth = 0; kth < 4; ++kth)
#pragma unroll
        for (int s = 0; s < 4; ++s) {
            int base = (((w * 6 + 2 + kth) * 4 + s) * 64 + l) * 8;
            wh[kth][s]  = *(const short8*)(whi + base);
            wl_[kth][s] = *(const short8*)(wlo + base);
        }

    int jl = 16 * w + (l & 15);
    float bv[4];
#pragma unroll
    for (int s = 0; s < 4; ++s) bv[s] = biasv[s * 128 + jl];

    int arow = l & 15;
    int g16  = (l >> 4) * 16;
    uint rowbase = (uint)arow * (LROW * 2);
    uint rswz    = (uint)(arow & 7) << 4;
    int hrow0 = (l >> 4) * 4;

    // x staging address (byte offset within a plane), swizzled
    int xr = tid >> 5;
    uint xw = ((uint)xr * (LROW * 2) + (uint)(tid & 31) * 4) ^ ((uint)(xr & 7) << 4);

    // h write offsets for r=0..3
    uint hwa[4];
#pragma unroll
    for (int r = 0; r < 4; ++r) {
        uint row = (uint)(hrow0 + r);
        hwa[r] = (row * (LROW * 2) + 128u + 2u * (uint)jl) ^ ((row & 7u) << 4);
    }

    float cst[4]  = {0.f, 0.f, 0.f, 0.f};
    float hreg[4] = {0.f, 0.f, 0.f, 0.f};

    // zero LDS (h regions must read 0 at t=0)
    for (int i = tid; i < 2 * 2 * PLANE; i += 512) ((ushort*)L)[i] = 0;

    // prologue: x(0) staged into buf0, vx holds x(1)
    size_t xoff0 = (size_t)b0 * 64 + (size_t)tid * 2;
    uint vx = *(const uint*)(xhi + xoff0);
    __syncthreads();                       // zeros visible
    *(uint*)((char*)&L[0][0][0][0] + xw) = vx;
    vx = *(const uint*)(xhi + xoff0 + 65536);
    __syncthreads();                       // x(0) visible

    for (int t = 0; t < T_STEPS; ++t) {
        int p = t & 1;
        const char* ph = (const char*)&L[p][0][0][0];
        const char* pl = (const char*)&L[p][1][0][0];
        char* qh = (char*)&L[p ^ 1][0][0][0];
        char* ql = (char*)&L[p ^ 1][1][0][0];

        // TOP of step: stage x(t+1) from regs; issue prefetch x(t+2) so it
        // has the whole step before the barrier's vmcnt drain.
        if (t < T_STEPS - 1) {
            *(uint*)(qh + xw) = vx;
            int tn = (t + 2 < T_STEPS) ? t + 2 : T_STEPS - 1;
            vx = *(const uint*)(xhi + xoff0 + (size_t)tn * 65536);
        }

        f32x4 accA[4], accB[4];
#pragma unroll
        for (int s = 0; s < 4; ++s) {
            accA[s] = (f32x4){bv[s], bv[s], bv[s], bv[s]};
            accB[s] = (f32x4){0.f, 0.f, 0.f, 0.f};
        }

        // x part (hi only) -> accA   [chain depth 2]
#pragma unroll
        for (int ktx = 0; ktx < 2; ++ktx) {
            short8 ax = *(const short8*)(ph + ((rowbase + (uint)ktx * 64 + g16) ^ rswz));
#pragma unroll
            for (int s = 0; s < 4; ++s)
                accA[s] = __builtin_amdgcn_mfma_f32_16x16x32_bf16(ax, wx[ktx][s], accA[s], 0, 0, 0);
        }
        // h part kt 0..1 -> accA (depth +6), kt 2..3 -> accB (depth 6)
#pragma unroll
        for (int kth = 0; kth < 2; ++kth) {
            uint ra = (rowbase + 128u + (uint)kth * 64 + g16) ^ rswz;
            short8 ah = *(const short8*)(ph + ra);
            short8 al = *(const short8*)(pl + ra);
#pragma unroll
            for (int s = 0; s < 4; ++s)
                accA[s] = __builtin_amdgcn_mfma_f32_16x16x32_bf16(ah, wh[kth][s], accA[s], 0, 0, 0);
#pragma unroll
            for (int s = 0; s < 4; ++s)
                accA[s] = __builtin_amdgcn_mfma_f32_16x16x32_bf16(ah, wl_[kth][s], accA[s], 0, 0, 0);
#pragma unroll
            for (int s = 0; s < 4; ++s)
                accA[s] = __builtin_amdgcn_mfma_f32_16x16x32_bf16(al, wh[kth][s], accA[s], 0, 0, 0);
        }
#pragma unroll
        for (int kth = 2; kth < 4; ++kth) {
            uint ra = (rowbase + 128u + (uint)kth * 64 + g16) ^ rswz;
            short8 ah = *(const short8*)(ph + ra);
            short8 al = *(const short8*)(pl + ra);
#pragma unroll
            for (int s = 0; s < 4; ++s)
                accB[s] = __builtin_amdgcn_mfma_f32_16x16x32_bf16(ah, wh[kth][s], accB[s], 0, 0, 0);
#pragma unroll
            for (int s = 0; s < 4; ++s)
                accB[s] = __builtin_amdgcn_mfma_f32_16x16x32_bf16(ah, wl_[kth][s], accB[s], 0, 0, 0);
#pragma unroll
            for (int s = 0; s < 4; ++s)
                accB[s] = __builtin_amdgcn_mfma_f32_16x16x32_bf16(al, wh[kth][s], accB[s], 0, 0, 0);
        }

        // pointwise LSTM cell (lane-local)
#pragma unroll
        for (int r = 0; r < 4; ++r) {
            float gi = sigf(accA[0][r] + accB[0][r]);
            float gf = sigf(accA[1][r] + accB[1][r]);
            float gg = tanhf_fast(accA[2][r] + accB[2][r]);
            float go = sigf(accA[3][r] + accB[3][r]);
            cst[r] = gf * cst[r] + gi * gg;
            hreg[r] = go * tanhf_fast(cst[r]);
        }

        if (t < T_STEPS - 1) {
            // stage h(t) hi/lo into next buffer
#pragma unroll
            for (int r = 0; r < 4; ++r) {
                float hv = hreg[r];
                ushort hh = f2bf(hv);
                *(ushort*)(qh + hwa[r]) = hh;
                *(ushort*)(ql + hwa[r]) = f2bf(hv - bf2f(hh));
            }
            __syncthreads();
        }
    }

#pragma unroll
    for (int r = 0; r < 4; ++r)
        hfin[(size_t)(b0 + hrow0 + r) * 128 + jl] = hreg[r];
}

// ---------------------------------------------------------------------------
// post: per row: u=tanh(W1c@h); v=W2@u; res=W0@h+127v; LN; linear; tile 196x.
// ---------------------------------------------------------------------------
__global__ __launch_bounds__(128) void post_kernel(const char* __restrict__ wsb,
                                                   const float* __restrict__ ln_g,
                                                   const float* __restrict__ ln_b,
                                                   const float* __restrict__ lin_b,
                                                   float* __restrict__ out) {
    const float* hfinal = (const float*)(wsb + OFF_HFIN);
    const float* W1cT   = (const float*)(wsb + OFF_W1CT);
    const float* W2T    = (const float*)(wsb + OFF_W2T);
    const float* W0T    = (const float*)(wsb + OFF_W0T);
    const float* linWT  = (const float*)(wsb + OFF_LINWT);

    __shared__ float sh[128], su[128], sres[128], spart[4];
    int b = blockIdx.x, f = threadIdx.x;

    sh[f] = hfinal[(size_t)b * 128 + f];
    __syncthreads();

    float acc = 0.f;
#pragma unroll 4
    for (int k = 0; k < 128; ++k) acc += W1cT[k * 128 + f] * sh[k];
    su[f] = tanhf_fast(acc);
    __syncthreads();

    float v = 0.f, r0 = 0.f;
#pragma unroll 4
    for (int k = 0; k < 128; ++k) {
        v  += W2T[k * 128 + f] * su[k];
        r0 += W0T[k * 128 + f] * sh[k];
    }
    float res = r0 + 127.f * v;

    int lane = f & 63, wid = f >> 6;
    float s = res;
#pragma unroll
    for (int off = 32; off > 0; off >>= 1) s += __shfl_down(s, off);
    if (lane == 0) spart[wid] = s;
    __syncthreads();
    float mu = (spart[0] + spart[1]) * (1.f / 128.f);
    float d = res - mu;
    float s2 = d * d;
#pragma unroll
    for (int off = 32; off > 0; off >>= 1) s2 += __shfl_down(s2, off);
    if (lane == 0) spart[2 + wid] = s2;
    __syncthreads();
    float var = (spart[2] + spart[3]) * (1.f / 128.f);
    float rn = d * rsqrtf(var + 1e-5f) * ln_g[f] + ln_b[f];
    sres[f] = rn;
    __syncthreads();

    float o = lin_b[f];
#pragma unroll 4
    for (int k = 0; k < 128; ++k) o += linWT[k * 128 + f] * sres[k];

    float* op = out + (size_t)b * 196 * 128 + f;
#pragma unroll 4
    for (int i = 0; i < 196; ++i) op[i * 128] = o;
}

// ---------------------------------------------------------------------------
extern "C" void kernel_launch(void* const* d_in, const int* in_sizes, int n_in,
                              void* d_out, int out_size, void* d_ws, size_t ws_size,
                              hipStream_t stream) {
    const float* x      = (const float*)d_in[0];
    const float* conv_w = (const float*)d_in[1];
    const float* conv_b = (const float*)d_in[2];
    const float* w_ih   = (const float*)d_in[3];
    const float* w_hh   = (const float*)d_in[4];
    const float* b_ih   = (const float*)d_in[5];
    const float* b_hh   = (const float*)d_in[6];
    const float* W1     = (const float*)d_in[7];
    const float* W2     = (const float*)d_in[8];
    const float* W0     = (const float*)d_in[9];
    const float* ln_g   = (const float*)d_in[10];
    const float* ln_b   = (const float*)d_in[11];
    const float* lin_w  = (const float*)d_in[12];
    const float* lin_b  = (const float*)d_in[13];
    char* wsb  = (char*)d_ws;
    float* out = (float*)d_out;

    prep_kernel<<<dim3(321), dim3(512), 0, stream>>>(w_ih, w_hh, b_ih, b_hh,
                                                     W1, W2, W0, lin_w, wsb);
    conv_kernel<<<dim3(1024), dim3(256), 0, stream>>>(x, conv_w, conv_b, wsb);
    lstm_mfma<<<dim3(64), dim3(512), 0, stream>>>(wsb, wsb);
    post_kernel<<<dim3(1024), dim3(128), 0, stream>>>(wsb, ln_g, ln_b, lin_b, out);
}